// Round 1
// baseline (338.732 us; speedup 1.0000x reference)
//
#include <hip/hip_runtime.h>
#include <hip/hip_bf16.h>
#include <stdint.h>

typedef float f32x4 __attribute__((ext_vector_type(4)));
typedef __bf16 bf16x8 __attribute__((ext_vector_type(8)));
typedef unsigned short ushort8 __attribute__((ext_vector_type(8)));

#define NB 8
#define NS 8192
#define ND 512
#define NM (NB * NS)      // 65536 rows
#define NK 512            // reduction dim

// ---------------- kernel 0: f32 -> bf16 (RNE) ----------------
__device__ __forceinline__ unsigned short f2bf(float f) {
  unsigned u = __float_as_uint(f);
  u += 0x7FFFu + ((u >> 16) & 1u);
  return (unsigned short)(u >> 16);
}

__global__ __launch_bounds__(256) void cvt_bf16(const float* __restrict__ src,
                                                unsigned short* __restrict__ dst,
                                                int n8) {
  int i = blockIdx.x * 256 + threadIdx.x;
  if (i >= n8) return;
  const float4* s = reinterpret_cast<const float4*>(src + (size_t)i * 8);
  float4 v0 = s[0], v1 = s[1];
  ushort8 o;
  o[0] = f2bf(v0.x); o[1] = f2bf(v0.y); o[2] = f2bf(v0.z); o[3] = f2bf(v0.w);
  o[4] = f2bf(v1.x); o[5] = f2bf(v1.y); o[6] = f2bf(v1.z); o[7] = f2bf(v1.w);
  *reinterpret_cast<ushort8*>(dst + (size_t)i * 8) = o;
}

// ---------------- kernel 1: bf16 GEMM + a/b epilogue ----------------
// C = x(65536x512) @ W^T(512x1024), paired-column tiling: block covers 128 rows x
// (64 hidden cols [n0,n0+64) + 64 gate cols [512+n0, 512+n0+64)).
// Epilogue: a = sigmoid(-gate), b = sigmoid(gate)*g(hidden); a->aw, b->bw.
__global__ __launch_bounds__(256) void gemm_ab(const unsigned short* __restrict__ xb,
                                               const unsigned short* __restrict__ wb,
                                               float* __restrict__ aw,
                                               float* __restrict__ bw) {
  __shared__ __align__(16) unsigned short lds[2 * 128 * 64]; // A tile 16KB | B tile 16KB
  float* gbuf = reinterpret_cast<float*>(lds);               // 32KB alias for gate exch

  const int tid = threadIdx.x;
  const int w = tid >> 6;         // wave 0..3
  const int lane = tid & 63;
  const int wr = w >> 1;          // row-half of tile
  const int wc = w & 1;           // col-half of tile (0: hidden cols, 1: gate cols)
  const int nblk = blockIdx.x & 7;
  const int mblk = blockIdx.x >> 3;
  const int m0 = mblk * 128;
  const int n0 = nblk * 64;       // channel base

  const int lrow = lane >> 3;         // 0..7 (row within wave's 8-row staging group)
  const int lcol = (lane & 7) * 8;    // 0..56 (bf16 col of this lane's 16B)

  f32x4 acc[4][4];
#pragma unroll
  for (int i = 0; i < 4; ++i)
#pragma unroll
    for (int j = 0; j < 4; ++j) acc[i][j] = (f32x4)0.0f;

  const int fr = lane & 15;   // fragment row/col
  const int kg = lane >> 4;   // k-group

  for (int kt = 0; kt < 8; ++kt) {
    const int k0 = kt * 64;
    // stage A and B tiles: 4 rounds, each wave fills 1KB (16B/lane), dest linear
#pragma unroll
    for (int i = 0; i < 4; ++i) {
      int row = i * 32 + w * 8 + lrow;
      const unsigned short* srcA = xb + (size_t)(m0 + row) * NK + k0 + lcol;
      __builtin_amdgcn_global_load_lds(
          (const __attribute__((address_space(1))) void*)srcA,
          (__attribute__((address_space(3))) void*)(lds + i * 2048 + w * 512),
          16, 0, 0);
      int e = (row < 64) ? (n0 + row) : (448 + n0 + row); // hidden rows | gate rows
      const unsigned short* srcB = wb + (size_t)e * NK + k0 + lcol;
      __builtin_amdgcn_global_load_lds(
          (const __attribute__((address_space(1))) void*)srcB,
          (__attribute__((address_space(3))) void*)(lds + 8192 + i * 2048 + w * 512),
          16, 0, 0);
    }
    __syncthreads();

    const unsigned short* ldsA = lds;
    const unsigned short* ldsB = lds + 8192;
#pragma unroll
    for (int kk = 0; kk < 64; kk += 32) {
      bf16x8 af[4], bf[4];
#pragma unroll
      for (int i = 0; i < 4; ++i) {
        int rowA = wr * 64 + i * 16 + fr;
        af[i] = *reinterpret_cast<const bf16x8*>(ldsA + rowA * 64 + kk + kg * 8);
        int rowB = wc * 64 + i * 16 + fr;
        bf[i] = *reinterpret_cast<const bf16x8*>(ldsB + rowB * 64 + kk + kg * 8);
      }
#pragma unroll
      for (int i = 0; i < 4; ++i)
#pragma unroll
        for (int j = 0; j < 4; ++j)
          acc[i][j] = __builtin_amdgcn_mfma_f32_16x16x32_bf16(af[i], bf[j], acc[i][j], 0, 0, 0);
    }
    __syncthreads();
  }

  // Epilogue: gate-half waves publish gate values to LDS.
  if (wc == 1) {
#pragma unroll
    for (int i = 0; i < 4; ++i)
#pragma unroll
      for (int j = 0; j < 4; ++j)
#pragma unroll
        for (int r = 0; r < 4; ++r) {
          int row = wr * 64 + i * 16 + kg * 4 + r;
          int dl = j * 16 + fr;
          gbuf[row * 64 + dl] = acc[i][j][r];
        }
  }
  __syncthreads();
  if (wc == 0) {
#pragma unroll
    for (int i = 0; i < 4; ++i)
#pragma unroll
      for (int j = 0; j < 4; ++j)
#pragma unroll
        for (int r = 0; r < 4; ++r) {
          int row = wr * 64 + i * 16 + kg * 4 + r;
          int dl = j * 16 + fr;
          float hid = acc[i][j][r];
          float gat = gbuf[row * 64 + dl];
          float a = 1.0f / (1.0f + __expf(gat));     // sigmoid(-gate)
          float z = 1.0f - a;                        // sigmoid(gate)
          float g = (hid >= 0.0f) ? (hid + 0.5f) : (1.0f / (1.0f + __expf(-hid)));
          float bb = z * g;
          size_t o = (size_t)(m0 + row) * ND + n0 + dl;
          aw[o] = a;
          bw[o] = bb;
        }
  }
}

// ---------------- kernel 2: per-chunk scan aggregates ----------------
// chunk L=128, 64 chunks per sequence. (A_c, B_c): h_end = A_c*h_start + B_c
__global__ __launch_bounds__(256) void scan_pass1(const float* __restrict__ aw,
                                                  const float* __restrict__ bw,
                                                  float* __restrict__ aggA,
                                                  float* __restrict__ aggB) {
  int bid = blockIdx.x;        // 8 * 64 * 2
  int b = bid >> 7;
  int rest = bid & 127;
  int c = rest >> 1;
  int half = rest & 1;
  int d = half * 256 + threadIdx.x;
  int base = (b * NS + c * 128) * ND + d;
  float A = 1.0f, Bc = 0.0f;
#pragma unroll 8
  for (int t = 0; t < 128; ++t) {
    float a = aw[base + t * ND];
    float v = bw[base + t * ND];
    Bc = fmaf(a, Bc, v);
    A *= a;
  }
  int o = (b * 64 + c) * ND + d;
  aggA[o] = A;
  aggB[o] = Bc;
}

// ---------------- kernel 3: prefix + final scan ----------------
__global__ __launch_bounds__(256) void scan_pass2(const float* __restrict__ aw,
                                                  const float* __restrict__ aggA,
                                                  const float* __restrict__ aggB,
                                                  float* __restrict__ outb,
                                                  float* __restrict__ nextp) {
  int bid = blockIdx.x;
  int b = bid >> 7;
  int rest = bid & 127;
  int c = rest >> 1;
  int half = rest & 1;
  int d = half * 256 + threadIdx.x;

  float h = 0.0f;
  for (int cc = 0; cc < c; ++cc) {
    int o = (b * 64 + cc) * ND + d;
    h = fmaf(aggA[o], h, aggB[o]);
  }
  int base = (b * NS + c * 128) * ND + d;
#pragma unroll 8
  for (int t = 0; t < 128; ++t) {
    int idx = base + t * ND;
    float a = aw[idx];
    float v = outb[idx];    // b_t (in-place: read b, write h)
    h = fmaf(a, h, v);
    outb[idx] = h;
  }
  if (c == 63) nextp[b * ND + d] = h;
}

// ---------------- launcher ----------------
extern "C" void kernel_launch(void* const* d_in, const int* in_sizes, int n_in,
                              void* d_out, int out_size, void* d_ws, size_t ws_size,
                              hipStream_t stream) {
  const float* x = (const float*)d_in[0];   // (8, 8192, 512) f32
  const float* W = (const float*)d_in[1];   // (1024, 512) f32
  float* out = (float*)d_out;               // 33554432 + 4096 f32

  char* ws = (char*)d_ws;
  unsigned short* xb = (unsigned short*)ws;                          // 64 MB
  unsigned short* wbf = (unsigned short*)(ws + (size_t)67108864);    // 1 MB
  float* aw = (float*)(ws + (size_t)67108864 + 1048576);             // 128 MB
  float* aggA = (float*)(ws + (size_t)67108864 + 1048576 + 134217728);
  float* aggB = aggA + NB * 64 * ND;                                 // 1 MB each
  float* bw = out;                                                   // reuse out as b
  float* nextp = out + (size_t)NM * ND;

  cvt_bf16<<<16384, 256, 0, stream>>>(x, xb, (NM * NK) / 8);
  cvt_bf16<<<256, 256, 0, stream>>>(W, wbf, (1024 * NK) / 8);
  gemm_ab<<<4096, 256, 0, stream>>>(xb, wbf, aw, bw);
  scan_pass1<<<1024, 256, 0, stream>>>(aw, bw, aggA, aggB);
  scan_pass2<<<1024, 256, 0, stream>>>(aw, aggA, aggB, bw, nextp);
}

// Round 3
// 286.387 us; speedup vs baseline: 1.1828x; 1.1828x over previous
//
#include <hip/hip_runtime.h>
#include <hip/hip_bf16.h>
#include <stdint.h>

typedef float f32x4 __attribute__((ext_vector_type(4)));
typedef __bf16 bf16x8 __attribute__((ext_vector_type(8)));
typedef unsigned short ushort8 __attribute__((ext_vector_type(8)));

#define NB 8
#define NS 8192
#define ND 512
#define NM (NB * NS)      // 65536 rows
#define NK 512            // reduction dim

// ---------------- f32 -> bf16 (RNE) ----------------
__device__ __forceinline__ unsigned short f2bf(float f) {
  unsigned u = __float_as_uint(f);
  u += 0x7FFFu + ((u >> 16) & 1u);
  return (unsigned short)(u >> 16);
}

__global__ __launch_bounds__(256) void cvt_bf16(const float* __restrict__ src,
                                                unsigned short* __restrict__ dst,
                                                int n8) {
  int i = blockIdx.x * 256 + threadIdx.x;
  if (i >= n8) return;
  const float4* s = reinterpret_cast<const float4*>(src + (size_t)i * 8);
  float4 v0 = s[0], v1 = s[1];
  ushort8 o;
  o[0] = f2bf(v0.x); o[1] = f2bf(v0.y); o[2] = f2bf(v0.z); o[3] = f2bf(v0.w);
  o[4] = f2bf(v1.x); o[5] = f2bf(v1.y); o[6] = f2bf(v1.z); o[7] = f2bf(v1.w);
  *reinterpret_cast<ushort8*>(dst + (size_t)i * 8) = o;
}

// ---------------- bf16 GEMM + a/b epilogue ----------------
// Block covers 128 rows x (64 hidden cols + matching 64 gate cols).
// LDS tiles XOR-swizzled (T2, both-sides via pre-swizzled global source).
// Grid XCD-swizzled (T1) so one mblk's 8 nblk-blocks share an XCD L2.
// Outputs a,b in bf16.
__global__ __launch_bounds__(256) void gemm_ab(const unsigned short* __restrict__ xb,
                                               const unsigned short* __restrict__ wb,
                                               unsigned short* __restrict__ aw,
                                               unsigned short* __restrict__ bw) {
  __shared__ __align__(16) unsigned short lds[2 * 128 * 64]; // A 16KB | B 16KB
  float* gbuf = reinterpret_cast<float*>(lds);               // 32KB alias (gate exch)

  const int tid = threadIdx.x;
  const int w = tid >> 6;
  const int lane = tid & 63;
  const int wr = w >> 1;          // row-half
  const int wc = w & 1;           // 0: hidden cols, 1: gate cols
  // T1 bijective XCD swizzle: 4096 = 512 mblk x 8 nblk
  const int orig = blockIdx.x;
  const int wg = (orig & 7) * 512 + (orig >> 3);
  const int mblk = wg >> 3;
  const int nblk = wg & 7;
  const int m0 = mblk * 128;
  const int n0 = nblk * 64;

  const int lrow = lane >> 3;                    // 0..7
  const int lcol = (((lane & 7) ^ lrow) * 8);    // pre-swizzled source column (bf16)

  f32x4 acc[4][4];
#pragma unroll
  for (int i = 0; i < 4; ++i)
#pragma unroll
    for (int j = 0; j < 4; ++j) acc[i][j] = (f32x4)0.0f;

  const int fr = lane & 15;
  const int kg = lane >> 4;

  for (int kt = 0; kt < 8; ++kt) {
    const int k0 = kt * 64;
#pragma unroll
    for (int i = 0; i < 4; ++i) {
      int row = i * 32 + w * 8 + lrow;
      const unsigned short* srcA = xb + (size_t)(m0 + row) * NK + k0 + lcol;
      __builtin_amdgcn_global_load_lds(
          (const __attribute__((address_space(1))) void*)srcA,
          (__attribute__((address_space(3))) void*)(lds + i * 2048 + w * 512),
          16, 0, 0);
      int e = (row < 64) ? (n0 + row) : (448 + n0 + row);
      const unsigned short* srcB = wb + (size_t)e * NK + k0 + lcol;
      __builtin_amdgcn_global_load_lds(
          (const __attribute__((address_space(1))) void*)srcB,
          (__attribute__((address_space(3))) void*)(lds + 8192 + i * 2048 + w * 512),
          16, 0, 0);
    }
    __syncthreads();

    const char* ldsA = (const char*)lds;
    const char* ldsB = (const char*)(lds + 8192);
#pragma unroll
    for (int kk = 0; kk < 64; kk += 32) {
      bf16x8 af[4], bfr[4];
#pragma unroll
      for (int i = 0; i < 4; ++i) {
        int rowA = wr * 64 + i * 16 + fr;
        int swzA = (kk * 2 + kg * 16) ^ ((rowA & 7) << 4);
        af[i] = *reinterpret_cast<const bf16x8*>(ldsA + rowA * 128 + swzA);
        int rowB = wc * 64 + i * 16 + fr;
        int swzB = (kk * 2 + kg * 16) ^ ((rowB & 7) << 4);
        bfr[i] = *reinterpret_cast<const bf16x8*>(ldsB + rowB * 128 + swzB);
      }
#pragma unroll
      for (int i = 0; i < 4; ++i)
#pragma unroll
        for (int j = 0; j < 4; ++j)
          acc[i][j] = __builtin_amdgcn_mfma_f32_16x16x32_bf16(af[i], bfr[j], acc[i][j], 0, 0, 0);
    }
    __syncthreads();
  }

  // gate-half waves publish gate values to LDS (swizzled to dodge 4-way conflicts)
  if (wc == 1) {
#pragma unroll
    for (int i = 0; i < 4; ++i)
#pragma unroll
      for (int j = 0; j < 4; ++j)
#pragma unroll
        for (int r = 0; r < 4; ++r) {
          int row = wr * 64 + i * 16 + kg * 4 + r;
          int dl = j * 16 + fr;
          int dsw = dl ^ (((row >> 2) & 3) << 4);
          gbuf[row * 64 + dsw] = acc[i][j][r];
        }
  }
  __syncthreads();
  if (wc == 0) {
#pragma unroll
    for (int i = 0; i < 4; ++i)
#pragma unroll
      for (int j = 0; j < 4; ++j)
#pragma unroll
        for (int r = 0; r < 4; ++r) {
          int row = wr * 64 + i * 16 + kg * 4 + r;
          int dl = j * 16 + fr;
          int dsw = dl ^ (((row >> 2) & 3) << 4);
          float hid = acc[i][j][r];
          float gat = gbuf[row * 64 + dsw];
          float a = 1.0f / (1.0f + __expf(gat));     // sigmoid(-gate)
          float z = 1.0f - a;                        // sigmoid(gate)
          float g = (hid >= 0.0f) ? (hid + 0.5f) : (1.0f / (1.0f + __expf(-hid)));
          float bb = z * g;
          size_t o = (size_t)(m0 + row) * ND + n0 + dl;
          aw[o] = f2bf(a);
          bw[o] = f2bf(bb);
        }
  }
}

// ---------------- scan pass1: per-chunk (A,B) aggregates ----------------
// chunk L=128, 64 chunks/seq; 2 channels per thread (uint = 2 bf16)
__global__ __launch_bounds__(256) void scan_pass1(const unsigned short* __restrict__ aw,
                                                  const unsigned short* __restrict__ bw,
                                                  float* __restrict__ aggA,
                                                  float* __restrict__ aggB) {
  int bid = blockIdx.x;        // 8*64
  int b = bid >> 6;
  int c = bid & 63;
  int d2 = threadIdx.x;        // channel-pair 0..255
  const uint32_t* ap = reinterpret_cast<const uint32_t*>(aw);
  const uint32_t* bp = reinterpret_cast<const uint32_t*>(bw);
  size_t base = (size_t)(b * NS + c * 128) * 256 + d2;
  float A0 = 1.0f, A1 = 1.0f, B0 = 0.0f, B1 = 0.0f;
#pragma unroll 8
  for (int t = 0; t < 128; ++t) {
    uint32_t ua = ap[base + (size_t)t * 256];
    uint32_t ub = bp[base + (size_t)t * 256];
    float a0 = __uint_as_float(ua << 16);
    float a1 = __uint_as_float(ua & 0xffff0000u);
    float v0 = __uint_as_float(ub << 16);
    float v1 = __uint_as_float(ub & 0xffff0000u);
    B0 = fmaf(a0, B0, v0); A0 *= a0;
    B1 = fmaf(a1, B1, v1); A1 *= a1;
  }
  int o = (b * 64 + c) * ND + d2 * 2;
  *reinterpret_cast<float2*>(&aggA[o]) = make_float2(A0, A1);
  *reinterpret_cast<float2*>(&aggB[o]) = make_float2(B0, B1);
}

// ---------------- scan pass2: prefix + rescan, write out f32 ----------------
__global__ __launch_bounds__(256) void scan_pass2(const unsigned short* __restrict__ aw,
                                                  const unsigned short* __restrict__ bw,
                                                  const float* __restrict__ aggA,
                                                  const float* __restrict__ aggB,
                                                  float* __restrict__ out,
                                                  float* __restrict__ nextp) {
  int bid = blockIdx.x;
  int b = bid >> 6;
  int c = bid & 63;
  int d2 = threadIdx.x;

  float h0 = 0.0f, h1 = 0.0f;
  for (int cc = 0; cc < c; ++cc) {
    int o = (b * 64 + cc) * ND + d2 * 2;
    float2 Aa = *reinterpret_cast<const float2*>(&aggA[o]);
    float2 Bb = *reinterpret_cast<const float2*>(&aggB[o]);
    h0 = fmaf(Aa.x, h0, Bb.x);
    h1 = fmaf(Aa.y, h1, Bb.y);
  }
  const uint32_t* ap = reinterpret_cast<const uint32_t*>(aw);
  const uint32_t* bp = reinterpret_cast<const uint32_t*>(bw);
  size_t base = (size_t)(b * NS + c * 128) * 256 + d2;
#pragma unroll 4
  for (int t = 0; t < 128; ++t) {
    uint32_t ua = ap[base + (size_t)t * 256];
    uint32_t ub = bp[base + (size_t)t * 256];
    float a0 = __uint_as_float(ua << 16);
    float a1 = __uint_as_float(ua & 0xffff0000u);
    float v0 = __uint_as_float(ub << 16);
    float v1 = __uint_as_float(ub & 0xffff0000u);
    h0 = fmaf(a0, h0, v0);
    h1 = fmaf(a1, h1, v1);
    *reinterpret_cast<float2*>(&out[(base + (size_t)t * 256) * 2]) = make_float2(h0, h1);
  }
  if (c == 63) {
    *reinterpret_cast<float2*>(&nextp[b * ND + d2 * 2]) = make_float2(h0, h1);
  }
}

// ---------------- launcher ----------------
extern "C" void kernel_launch(void* const* d_in, const int* in_sizes, int n_in,
                              void* d_out, int out_size, void* d_ws, size_t ws_size,
                              hipStream_t stream) {
  const float* x = (const float*)d_in[0];   // (8, 8192, 512) f32
  const float* W = (const float*)d_in[1];   // (1024, 512) f32
  float* out = (float*)d_out;               // 33554432 + 4096 f32

  char* ws = (char*)d_ws;
  unsigned short* xb  = (unsigned short*)ws;                              // 64 MB
  unsigned short* wbf = (unsigned short*)(ws + (size_t)64 * 1024 * 1024); // 1 MB
  unsigned short* aw  = (unsigned short*)(ws + (size_t)65 * 1024 * 1024); // 64 MB
  unsigned short* bw  = (unsigned short*)(ws + (size_t)129 * 1024 * 1024);// 64 MB
  float* aggA = (float*)(ws + (size_t)193 * 1024 * 1024);                 // 1 MB
  float* aggB = (float*)(ws + (size_t)194 * 1024 * 1024);                 // 1 MB
  float* nextp = out + (size_t)NM * ND;

  cvt_bf16<<<16384, 256, 0, stream>>>(x, xb, (NM * NK) / 8);
  cvt_bf16<<<256, 256, 0, stream>>>(W, wbf, (1024 * NK) / 8);
  gemm_ab<<<4096, 256, 0, stream>>>(xb, wbf, aw, bw);
  scan_pass1<<<512, 256, 0, stream>>>(aw, bw, aggA, aggB);
  scan_pass2<<<512, 256, 0, stream>>>(aw, bw, aggA, aggB, out, nextp);
}